// Round 4
// baseline (314.361 us; speedup 1.0000x reference)
//
#include <hip/hip_runtime.h>
#include <hip/hip_bf16.h>
#include <math.h>

// Problem constants (fixed by the reference)
#define TT 4096   // tokens = B*S
#define PP 8192   // pairs  = TT*K
#define DD 1024   // model dim
#define HH 2048   // expert hidden
#define EE 8      // experts
#define CC1 4096  // 2H (up-proj width)

typedef __attribute__((ext_vector_type(8))) short s16x8;
typedef __attribute__((ext_vector_type(4))) float f32x4;

// ---------------- workspace layout (bytes) ----------------
#define W1T_OFF   0ull                                   // bf16 [E][4096][1024]  64 MB
#define W2T_OFF   (W1T_OFF + (size_t)EE*DD*CC1*2)        // bf16 [E][1024][2048]  32 MB
#define XB_OFF    (W2T_OFF + (size_t)EE*HH*DD*2)         // bf16 [T][1024]         8 MB
#define ABUF_OFF  (XB_OFF  + (size_t)TT*DD*2)            // bf16 [P][2048]        32 MB
#define META_OFF  (ABUF_OFF + (size_t)PP*HH*2)           // int meta[512] (2 KB)
#define PAIR_OFF  (META_OFF + 2048)                      // int [P]
#define POS_OFF   (PAIR_OFF + (size_t)PP*4)              // int [P]

#define VMCNT(N) asm volatile("s_waitcnt vmcnt(" #N ")" ::: "memory")
#define CFENCE() asm volatile("" ::: "memory")

__device__ __forceinline__ unsigned short f2bf(float f) {
  union { float f; unsigned u; } a; a.f = f;
  unsigned u = a.u;
  unsigned r = u + 0x7FFFu + ((u >> 16) & 1u);   // round-to-nearest-even
  return (unsigned short)(r >> 16);
}

// async global->LDS, 16B per lane; LDS dest must be wave-uniform base + lane*16
__device__ __forceinline__ void gload16(const void* g, void* l) {
  __builtin_amdgcn_global_load_lds(
      (const __attribute__((address_space(1))) void*)(uintptr_t)g,
      (__attribute__((address_space(3))) void*)(unsigned)(uintptr_t)l,
      16, 0, 0);
}

// ---------------- x -> bf16 ----------------
__global__ void k_cvt_x(const float* __restrict__ in, unsigned short* __restrict__ out, int n4) {
  int i = blockIdx.x * blockDim.x + threadIdx.x;
  if (i >= n4) return;
  float4 v = reinterpret_cast<const float4*>(in)[i];
  ushort4 o;
  o.x = f2bf(v.x); o.y = f2bf(v.y); o.z = f2bf(v.z); o.w = f2bf(v.w);
  reinterpret_cast<ushort4*>(out)[i] = o;
}

// ---------------- zero y ----------------
__global__ void k_zero(float4* __restrict__ y, int n4) {
  int i = blockIdx.x * blockDim.x + threadIdx.x;
  if (i < n4) y[i] = (float4){0.f, 0.f, 0.f, 0.f};
}

// ---------------- W [R][C] f32 -> Wt [C][R] bf16 (per matrix in grid.z) ----------------
__global__ __launch_bounds__(256) void k_transpose(const float* __restrict__ in,
                                                   unsigned short* __restrict__ out,
                                                   int R, int C) {
  __shared__ float t[64][65];
  const size_t mbase = (size_t)blockIdx.z * (size_t)R * (size_t)C;
  int c0 = blockIdx.x * 64, r0 = blockIdx.y * 64;
  int tid = threadIdx.x;
#pragma unroll
  for (int i = 0; i < 4; ++i) {
    int ch = tid + i * 256;            // 1024 chunks of float4
    int row = ch >> 4, c4 = (ch & 15) * 4;
    float4 v = *reinterpret_cast<const float4*>(&in[mbase + (size_t)(r0 + row) * C + c0 + c4]);
    t[row][c4] = v.x; t[row][c4 + 1] = v.y; t[row][c4 + 2] = v.z; t[row][c4 + 3] = v.w;
  }
  __syncthreads();
#pragma unroll
  for (int i = 0; i < 4; ++i) {
    int ch = tid + i * 256;
    int c = ch >> 4, rb = (ch & 15) * 4;
    ushort4 o;
    o.x = f2bf(t[rb][c]); o.y = f2bf(t[rb + 1][c]);
    o.z = f2bf(t[rb + 2][c]); o.w = f2bf(t[rb + 3][c]);
    *reinterpret_cast<ushort4*>(&out[mbase + (size_t)(c0 + c) * R + r0 + rb]) = o;
  }
}

// ---------------- routing: bucket pairs by expert, tile lists (256 & 128), inverse perm ----
// meta[0]=ntiles256; meta[1..9]=offsets[0..8]; meta[10]=ntiles128;
// meta[16+2i]/(17+2i) = (expert,q0) 256-tiles; meta[128+2i]/(129+2i) = 128-tiles
__global__ void k_route(const int* __restrict__ eidx, int* __restrict__ meta,
                        int* __restrict__ plist, int* __restrict__ pos) {
  __shared__ int cnt[EE], off[EE + 1], cur[EE];
  int tid = threadIdx.x;
  if (tid < EE) { cnt[tid] = 0; cur[tid] = 0; }
  __syncthreads();
  for (int p = tid; p < PP; p += blockDim.x) atomicAdd(&cnt[eidx[p]], 1);
  __syncthreads();
  if (tid == 0) {
    int s = 0;
    for (int e = 0; e < EE; ++e) { off[e] = s; s += cnt[e]; }
    off[EE] = s;
    int n256 = 0;
    for (int e = 0; e < EE; ++e)
      for (int r = 0; r < cnt[e]; r += 256) {
        meta[16 + 2*n256] = e; meta[17 + 2*n256] = off[e] + r; ++n256;
      }
    meta[0] = n256;
    int n128 = 0;
    for (int e = 0; e < EE; ++e)
      for (int r = 0; r < cnt[e]; r += 128) {
        meta[128 + 2*n128] = e; meta[129 + 2*n128] = off[e] + r; ++n128;
      }
    meta[10] = n128;
    for (int e = 0; e <= EE; ++e) meta[1 + e] = off[e];
  }
  __syncthreads();
  for (int p = tid; p < PP; p += blockDim.x) {
    int e = eidx[p];
    int q = off[e] + atomicAdd(&cur[e], 1);
    plist[q] = p;
    pos[p] = q;
  }
}

// ---------------- GEMM1: up = x @ W1[e], fused GLU + gate, bf16 out (sorted order) ----------
// 256x128 tile (64 h-cols + paired 64 g-cols), BK=64, 8 waves (4Mx2N),
// depth-2 prefetch (3 LDS buffers), counted vmcnt(6) + raw s_barrier (never drain in-loop),
// T2 XOR-swizzle: linear gload_lds dest + pre-swizzled global source + swizzled ds_read.
// grid: (40 row-tiles, 32 col-tiles); block 512
__global__ __launch_bounds__(512) void k_gemm1(
    const unsigned short* __restrict__ xb,     // [T][1024] bf16
    const unsigned short* __restrict__ w1t,    // [E][4096][1024] bf16 ([col][k])
    const float* __restrict__ gates,           // [P] f32
    const int* __restrict__ meta,
    const int* __restrict__ plist,
    unsigned short* __restrict__ abuf)         // [P][2048] bf16
{
  const int nt = meta[0];
  const int tb = blockIdx.x;
  if (tb >= nt) return;
  const int e  = meta[16 + 2*tb];
  const int q0 = meta[17 + 2*tb];
  const int nrows = min(256, meta[2 + e] - q0);
  const int c0 = blockIdx.y * 64;              // h-col base

  __shared__ unsigned short As[3][256 * 64];   // 96 KB
  __shared__ unsigned short Bs[3][128 * 64];   // 48 KB

  const int tid = threadIdx.x;                 // 0..511
  const int wave = tid >> 6, lane = tid & 63;
  const int l15 = lane & 15, l4 = lane >> 4;
  const int wr = wave >> 1, wc = wave & 1;     // 4M x 2N wave grid

  const unsigned short* w1e = w1t + (size_t)e * CC1 * DD;

  // staging sources: A 4 chunks, B 2 chunks of 16B per thread per K-step.
  // global k-slot pre-swizzled so that swizzled ds_read sees the right data.
  const unsigned short* aga[4];
  const unsigned short* bga[2];
#pragma unroll
  for (int i = 0; i < 4; ++i) {
    int c = tid + i * 512;                     // 0..2047
    int row = c >> 3;                          // 0..255
    int ko = ((c & 7) ^ (row & 7)) * 8;
    int r = row < nrows ? row : 0;
    int p = plist[q0 + r];
    aga[i] = xb + (size_t)(p >> 1) * DD + ko;
  }
#pragma unroll
  for (int i = 0; i < 2; ++i) {
    int c = tid + i * 512;                     // 0..1023
    int row = c >> 3;                          // 0..127
    int ko = ((c & 7) ^ (row & 7)) * 8;
    int u = row & 63, wcq = row >> 6;
    int col = (u < 32) ? (c0 + wcq * 32 + u) : (HH + c0 + wcq * 32 + (u - 32));
    bga[i] = w1e + (size_t)col * DD + ko;
  }

  f32x4 acc[4][4];
#pragma unroll
  for (int a = 0; a < 4; ++a)
#pragma unroll
    for (int b = 0; b < 4; ++b) acc[a][b] = (f32x4)0.0f;

  auto stage = [&](int kk, unsigned short* pa, unsigned short* pb) {
#pragma unroll
    for (int i = 0; i < 4; ++i) gload16(aga[i] + kk, pa + (tid + i * 512) * 8);
#pragma unroll
    for (int i = 0; i < 2; ++i) gload16(bga[i] + kk, pb + (tid + i * 512) * 8);
  };

  auto compute_tile = [&](const unsigned short* sa, const unsigned short* sb) {
    const char* A8 = (const char*)sa;
    const char* B8 = (const char*)sb;
#pragma unroll
    for (int ks = 0; ks < 2; ++ks) {
      s16x8 af[4], bfr[4];
#pragma unroll
      for (int rf = 0; rf < 4; ++rf) {
        int row = wr * 64 + rf * 16 + l15;
        af[rf] = *(const s16x8*)(A8 + ((row * 128 + ks * 64 + l4 * 16) ^ ((row & 7) << 4)));
      }
#pragma unroll
      for (int cf = 0; cf < 4; ++cf) {
        int row = wc * 64 + cf * 16 + l15;
        bfr[cf] = *(const s16x8*)(B8 + ((row * 128 + ks * 64 + l4 * 16) ^ ((row & 7) << 4)));
      }
#pragma unroll
      for (int rf = 0; rf < 4; ++rf)
#pragma unroll
        for (int cf = 0; cf < 4; ++cf)
          acc[rf][cf] = __builtin_amdgcn_mfma_f32_16x16x32_bf16(af[rf], bfr[cf], acc[rf][cf], 0, 0, 0);
    }
  };

  unsigned short *a0 = As[0], *a1 = As[1], *a2 = As[2];
  unsigned short *b0 = Bs[0], *b1 = Bs[1], *b2 = Bs[2];

  stage(0, a0, b0);
  stage(64, a1, b1);
  VMCNT(6);                                    // tile 0 landed; tile 1 may fly
  __builtin_amdgcn_s_barrier();
  CFENCE();

  for (int kt = 0; kt < DD / 64 - 2; ++kt) {   // kt = 0..13
    stage((kt + 2) * 64, a2, b2);              // prefetch depth 2
    compute_tile(a0, b0);
    VMCNT(6);                                  // all but newest K-tile landed
    __builtin_amdgcn_s_barrier();
    CFENCE();
    unsigned short* t;
    t = a0; a0 = a1; a1 = a2; a2 = t;
    t = b0; b0 = b1; b1 = b2; b2 = t;
  }
  compute_tile(a0, b0);                        // tile NT-2
  VMCNT(0);
  __builtin_amdgcn_s_barrier();
  CFENCE();
  compute_tile(a1, b1);                        // tile NT-1

  // Epilogue: a = gelu_exact(h) * (g+1) * gate, bf16.
  // acc[rf][cf]: cf 0,1 = h cols, cf 2,3 = matching g cols (same wave).
#pragma unroll
  for (int rf = 0; rf < 4; ++rf) {
#pragma unroll
    for (int i = 0; i < 4; ++i) {
      int r = wr * 64 + rf * 16 + l4 * 4 + i;
      if (r < nrows) {
        int q = q0 + r;
        float gt = gates[plist[q]];
        unsigned short* orow = abuf + (size_t)q * HH + c0 + wc * 32 + l15;
#pragma unroll
        for (int cf = 0; cf < 2; ++cf) {
          float hv = acc[rf][cf][i];
          float gv = acc[rf][cf + 2][i];
          float av = 0.5f * hv * (1.0f + erff(hv * 0.70710678118654752f)) * (gv + 1.0f) * gt;
          orow[cf * 16] = f2bf(av);
        }
      }
    }
  }
}

// ---------------- GEMM2: y[token] += a @ W2[e] (atomic combine, gate pre-applied) ---------
// 128x128 tile, depth-1 dbuf (2 blocks/CU); grid: (72 tiles, 8 col-tiles); block 256
__global__ __launch_bounds__(256) void k_gemm2(
    const unsigned short* __restrict__ abuf,   // [P][2048] bf16
    const unsigned short* __restrict__ w2t,    // [E][1024][2048] bf16 ([col][k])
    const int* __restrict__ meta,
    const int* __restrict__ plist,
    float* __restrict__ y)                     // [T][1024] f32 (pre-zeroed)
{
  const int nt = meta[10];
  const int tb = blockIdx.x;
  if (tb >= nt) return;
  const int e  = meta[128 + 2*tb];
  const int q0 = meta[129 + 2*tb];
  const int nrows = min(128, meta[2 + e] - q0);
  const int c0 = blockIdx.y * 128;

  __shared__ unsigned short Asm[2][128 * 64];
  __shared__ unsigned short Bsm[2][128 * 64];

  const int tid = threadIdx.x;
  const int wave = tid >> 6, lane = tid & 63;
  const int l15 = lane & 15, l4 = lane >> 4;
  const int wr = wave >> 1, wc = wave & 1;

  const unsigned short* w2e = w2t + (size_t)e * DD * HH;

  const unsigned short* aga[4];
  const unsigned short* bga[4];
#pragma unroll
  for (int i = 0; i < 4; ++i) {
    int c = tid + i * 256;
    int row = c >> 3;
    int ko = (c & 7) * 8;
    int r = row < nrows ? row : 0;
    aga[i] = abuf + (size_t)(q0 + r) * HH + ko;
    bga[i] = w2e + (size_t)(c0 + row) * HH + ko;
  }

  f32x4 acc[4][4];
#pragma unroll
  for (int a = 0; a < 4; ++a)
#pragma unroll
    for (int b = 0; b < 4; ++b) acc[a][b] = (f32x4)0.0f;

#pragma unroll
  for (int i = 0; i < 4; ++i) {
    int c = tid + i * 256;
    gload16(aga[i], &Asm[0][c * 8]);
    gload16(bga[i], &Bsm[0][c * 8]);
  }
  __syncthreads();

  int cur = 0;
  for (int kt = 0; kt < HH / 64 - 1; ++kt) {
    const int kk = (kt + 1) * 64;
#pragma unroll
    for (int i = 0; i < 4; ++i) {
      int c = tid + i * 256;
      gload16(aga[i] + kk, &Asm[cur ^ 1][c * 8]);
      gload16(bga[i] + kk, &Bsm[cur ^ 1][c * 8]);
    }
#pragma unroll
    for (int ks = 0; ks < 2; ++ks) {
      s16x8 af[4], bfr[4];
#pragma unroll
      for (int rf = 0; rf < 4; ++rf)
        af[rf] = *reinterpret_cast<const s16x8*>(&Asm[cur][(wr * 64 + rf * 16 + l15) * 64 + ks * 32 + l4 * 8]);
#pragma unroll
      for (int cf = 0; cf < 4; ++cf)
        bfr[cf] = *reinterpret_cast<const s16x8*>(&Bsm[cur][(wc * 64 + cf * 16 + l15) * 64 + ks * 32 + l4 * 8]);
#pragma unroll
      for (int rf = 0; rf < 4; ++rf)
#pragma unroll
        for (int cf = 0; cf < 4; ++cf)
          acc[rf][cf] = __builtin_amdgcn_mfma_f32_16x16x32_bf16(af[rf], bfr[cf], acc[rf][cf], 0, 0, 0);
    }
    __syncthreads();
    cur ^= 1;
  }
#pragma unroll
  for (int ks = 0; ks < 2; ++ks) {
    s16x8 af[4], bfr[4];
#pragma unroll
    for (int rf = 0; rf < 4; ++rf)
      af[rf] = *reinterpret_cast<const s16x8*>(&Asm[cur][(wr * 64 + rf * 16 + l15) * 64 + ks * 32 + l4 * 8]);
#pragma unroll
    for (int cf = 0; cf < 4; ++cf)
      bfr[cf] = *reinterpret_cast<const s16x8*>(&Bsm[cur][(wc * 64 + cf * 16 + l15) * 64 + ks * 32 + l4 * 8]);
#pragma unroll
    for (int rf = 0; rf < 4; ++rf)
#pragma unroll
      for (int cf = 0; cf < 4; ++cf)
        acc[rf][cf] = __builtin_amdgcn_mfma_f32_16x16x32_bf16(af[rf], bfr[cf], acc[rf][cf], 0, 0, 0);
  }

  // atomic combine straight into y (saves the down[] round-trip + combine kernel)
#pragma unroll
  for (int rf = 0; rf < 4; ++rf) {
#pragma unroll
    for (int i = 0; i < 4; ++i) {
      int r = wr * 64 + rf * 16 + l4 * 4 + i;
      if (r < nrows) {
        int q = q0 + r;
        int p = plist[q];
        float* yrow = y + (size_t)(p >> 1) * DD + c0 + wc * 64 + l15;
#pragma unroll
        for (int cf = 0; cf < 4; ++cf) atomicAdd(&yrow[cf * 16], acc[rf][cf][i]);
      }
    }
  }
}

extern "C" void kernel_launch(void* const* d_in, const int* in_sizes, int n_in,
                              void* d_out, int out_size, void* d_ws, size_t ws_size,
                              hipStream_t stream) {
  const float* x  = (const float*)d_in[0];
  const float* ep = (const float*)d_in[1];
  const int*   ei = (const int*)d_in[2];
  const float* W1 = (const float*)d_in[3];
  const float* W2 = (const float*)d_in[4];
  float* y = (float*)d_out;
  char* ws = (char*)d_ws;

  unsigned short* w1t = (unsigned short*)(ws + W1T_OFF);
  unsigned short* w2t = (unsigned short*)(ws + W2T_OFF);
  unsigned short* xb  = (unsigned short*)(ws + XB_OFF);
  unsigned short* ab  = (unsigned short*)(ws + ABUF_OFF);
  int* meta   = (int*)(ws + META_OFF);
  int* plist  = (int*)(ws + PAIR_OFF);
  int* pos    = (int*)(ws + POS_OFF);
  (void)pos;

  hipLaunchKernelGGL(k_cvt_x, dim3(TT * DD / 4 / 256), dim3(256), 0, stream,
                     x, xb, TT * DD / 4);
  hipLaunchKernelGGL(k_zero, dim3(TT * DD / 4 / 256), dim3(256), 0, stream,
                     (float4*)y, TT * DD / 4);
  hipLaunchKernelGGL(k_transpose, dim3(CC1 / 64, DD / 64, EE), dim3(256), 0, stream,
                     W1, w1t, DD, CC1);
  hipLaunchKernelGGL(k_transpose, dim3(DD / 64, HH / 64, EE), dim3(256), 0, stream,
                     W2, w2t, HH, DD);
  hipLaunchKernelGGL(k_route, dim3(1), dim3(256), 0, stream, ei, meta, plist, pos);
  hipLaunchKernelGGL(k_gemm1, dim3(40, 32), dim3(512), 0, stream,
                     xb, w1t, ep, meta, plist, ab);
  hipLaunchKernelGGL(k_gemm2, dim3(72, 8), dim3(256), 0, stream,
                     ab, w2t, meta, plist, y);
}

// Round 5
// 285.616 us; speedup vs baseline: 1.1006x; 1.1006x over previous
//
#include <hip/hip_runtime.h>
#include <hip/hip_bf16.h>
#include <math.h>

// Problem constants (fixed by the reference)
#define TT 4096   // tokens = B*S
#define PP 8192   // pairs  = TT*K
#define DD 1024   // model dim
#define HH 2048   // expert hidden
#define EE 8      // experts
#define CC1 4096  // 2H (up-proj width)

typedef __attribute__((ext_vector_type(8))) short s16x8;
typedef __attribute__((ext_vector_type(4))) float f32x4;

// ---------------- workspace layout (bytes) ----------------
#define W1T_OFF   0ull                                   // bf16 [E][4096][1024]  64 MB
#define W2T_OFF   (W1T_OFF + (size_t)EE*DD*CC1*2)        // bf16 [E][1024][2048]  32 MB
#define XB_OFF    (W2T_OFF + (size_t)EE*HH*DD*2)         // bf16 [T][1024]         8 MB
#define ABUF_OFF  (XB_OFF  + (size_t)TT*DD*2)            // bf16 [P][2048]        32 MB
#define DOWN_OFF  (ABUF_OFF + (size_t)PP*HH*2)           // f32  [P][1024]        32 MB
#define META_OFF  (DOWN_OFF + (size_t)PP*DD*4)           // int meta[512] (2 KB)
#define PAIR_OFF  (META_OFF + 2048)                      // int [P]
#define POS_OFF   (PAIR_OFF + (size_t)PP*4)              // int [P]

#define VMCNT(N) asm volatile("s_waitcnt vmcnt(" #N ")" ::: "memory")
#define CFENCE() asm volatile("" ::: "memory")

__device__ __forceinline__ unsigned short f2bf(float f) {
  union { float f; unsigned u; } a; a.f = f;
  unsigned u = a.u;
  unsigned r = u + 0x7FFFu + ((u >> 16) & 1u);   // round-to-nearest-even
  return (unsigned short)(r >> 16);
}

// async global->LDS, 16B per lane; LDS dest must be wave-uniform base + lane*16
__device__ __forceinline__ void gload16(const void* g, void* l) {
  __builtin_amdgcn_global_load_lds(
      (const __attribute__((address_space(1))) void*)(uintptr_t)g,
      (__attribute__((address_space(3))) void*)(unsigned)(uintptr_t)l,
      16, 0, 0);
}

// ---------------- x -> bf16 ----------------
__global__ void k_cvt_x(const float* __restrict__ in, unsigned short* __restrict__ out, int n4) {
  int i = blockIdx.x * blockDim.x + threadIdx.x;
  if (i >= n4) return;
  float4 v = reinterpret_cast<const float4*>(in)[i];
  ushort4 o;
  o.x = f2bf(v.x); o.y = f2bf(v.y); o.z = f2bf(v.z); o.w = f2bf(v.w);
  reinterpret_cast<ushort4*>(out)[i] = o;
}

// ---------------- W [R][C] f32 -> Wt [C][R] bf16 (per matrix in grid.z) ----------------
__global__ __launch_bounds__(256) void k_transpose(const float* __restrict__ in,
                                                   unsigned short* __restrict__ out,
                                                   int R, int C) {
  __shared__ float t[64][65];
  const size_t mbase = (size_t)blockIdx.z * (size_t)R * (size_t)C;
  int c0 = blockIdx.x * 64, r0 = blockIdx.y * 64;
  int tid = threadIdx.x;
#pragma unroll
  for (int i = 0; i < 4; ++i) {
    int ch = tid + i * 256;            // 1024 chunks of float4
    int row = ch >> 4, c4 = (ch & 15) * 4;
    float4 v = *reinterpret_cast<const float4*>(&in[mbase + (size_t)(r0 + row) * C + c0 + c4]);
    t[row][c4] = v.x; t[row][c4 + 1] = v.y; t[row][c4 + 2] = v.z; t[row][c4 + 3] = v.w;
  }
  __syncthreads();
#pragma unroll
  for (int i = 0; i < 4; ++i) {
    int ch = tid + i * 256;
    int c = ch >> 4, rb = (ch & 15) * 4;
    ushort4 o;
    o.x = f2bf(t[rb][c]); o.y = f2bf(t[rb + 1][c]);
    o.z = f2bf(t[rb + 2][c]); o.w = f2bf(t[rb + 3][c]);
    *reinterpret_cast<ushort4*>(&out[mbase + (size_t)(c0 + c) * R + r0 + rb]) = o;
  }
}

// ---------------- routing: bucket pairs by expert, 256-row tile list, inverse perm ----------
// meta[0]=ntiles256; meta[1..9]=offsets[0..8]; meta[16+2i]/(17+2i) = (expert,q0)
__global__ void k_route(const int* __restrict__ eidx, int* __restrict__ meta,
                        int* __restrict__ plist, int* __restrict__ pos) {
  __shared__ int cnt[EE], off[EE + 1], cur[EE];
  int tid = threadIdx.x;
  if (tid < EE) { cnt[tid] = 0; cur[tid] = 0; }
  __syncthreads();
  for (int p = tid; p < PP; p += blockDim.x) atomicAdd(&cnt[eidx[p]], 1);
  __syncthreads();
  if (tid == 0) {
    int s = 0;
    for (int e = 0; e < EE; ++e) { off[e] = s; s += cnt[e]; }
    off[EE] = s;
    int n256 = 0;
    for (int e = 0; e < EE; ++e)
      for (int r = 0; r < cnt[e]; r += 256) {
        meta[16 + 2*n256] = e; meta[17 + 2*n256] = off[e] + r; ++n256;
      }
    meta[0] = n256;
    for (int e = 0; e <= EE; ++e) meta[1 + e] = off[e];
  }
  __syncthreads();
  for (int p = tid; p < PP; p += blockDim.x) {
    int e = eidx[p];
    int q = off[e] + atomicAdd(&cur[e], 1);
    plist[q] = p;
    pos[p] = q;
  }
}

// ---------------- GEMM1: up = x @ W1[e], fused GLU + gate, bf16 out (sorted order) ----------
// 256x128 tile (64 h-cols + paired 64 g-cols), BK=64, 8 waves (4Mx2N),
// depth-2 prefetch (3 LDS buffers), counted vmcnt(6) + raw s_barrier,
// T2 XOR-swizzle (linear gload_lds dest + pre-swizzled global src + swizzled ds_read),
// T5 setprio around MFMA clusters.
// grid: (40 row-tiles, 32 col-tiles); block 512
__global__ __launch_bounds__(512) void k_gemm1(
    const unsigned short* __restrict__ xb,     // [T][1024] bf16
    const unsigned short* __restrict__ w1t,    // [E][4096][1024] bf16 ([col][k])
    const float* __restrict__ gates,           // [P] f32
    const int* __restrict__ meta,
    const int* __restrict__ plist,
    unsigned short* __restrict__ abuf)         // [P][2048] bf16
{
  const int nt = meta[0];
  const int tb = blockIdx.x;
  if (tb >= nt) return;
  const int e  = meta[16 + 2*tb];
  const int q0 = meta[17 + 2*tb];
  const int nrows = min(256, meta[2 + e] - q0);
  const int c0 = blockIdx.y * 64;              // h-col base

  __shared__ unsigned short As[3][256 * 64];   // 96 KB
  __shared__ unsigned short Bs[3][128 * 64];   // 48 KB

  const int tid = threadIdx.x;                 // 0..511
  const int wave = tid >> 6, lane = tid & 63;
  const int l15 = lane & 15, l4 = lane >> 4;
  const int wr = wave >> 1, wc = wave & 1;     // 4M x 2N wave grid

  const unsigned short* w1e = w1t + (size_t)e * CC1 * DD;

  const unsigned short* aga[4];
  const unsigned short* bga[2];
#pragma unroll
  for (int i = 0; i < 4; ++i) {
    int c = tid + i * 512;                     // 0..2047
    int row = c >> 3;                          // 0..255
    int ko = ((c & 7) ^ (row & 7)) * 8;
    int r = row < nrows ? row : 0;
    int p = plist[q0 + r];
    aga[i] = xb + (size_t)(p >> 1) * DD + ko;
  }
#pragma unroll
  for (int i = 0; i < 2; ++i) {
    int c = tid + i * 512;                     // 0..1023
    int row = c >> 3;                          // 0..127
    int ko = ((c & 7) ^ (row & 7)) * 8;
    int u = row & 63, wcq = row >> 6;
    int col = (u < 32) ? (c0 + wcq * 32 + u) : (HH + c0 + wcq * 32 + (u - 32));
    bga[i] = w1e + (size_t)col * DD + ko;
  }

  f32x4 acc[4][4];
#pragma unroll
  for (int a = 0; a < 4; ++a)
#pragma unroll
    for (int b = 0; b < 4; ++b) acc[a][b] = (f32x4)0.0f;

  auto stage = [&](int kk, unsigned short* pa, unsigned short* pb) {
#pragma unroll
    for (int i = 0; i < 4; ++i) gload16(aga[i] + kk, pa + (tid + i * 512) * 8);
#pragma unroll
    for (int i = 0; i < 2; ++i) gload16(bga[i] + kk, pb + (tid + i * 512) * 8);
  };

  auto compute_tile = [&](const unsigned short* sa, const unsigned short* sb) {
    const char* A8 = (const char*)sa;
    const char* B8 = (const char*)sb;
#pragma unroll
    for (int ks = 0; ks < 2; ++ks) {
      s16x8 af[4], bfr[4];
#pragma unroll
      for (int rf = 0; rf < 4; ++rf) {
        int row = wr * 64 + rf * 16 + l15;
        af[rf] = *(const s16x8*)(A8 + ((row * 128 + ks * 64 + l4 * 16) ^ ((row & 7) << 4)));
      }
#pragma unroll
      for (int cf = 0; cf < 4; ++cf) {
        int row = wc * 64 + cf * 16 + l15;
        bfr[cf] = *(const s16x8*)(B8 + ((row * 128 + ks * 64 + l4 * 16) ^ ((row & 7) << 4)));
      }
      __builtin_amdgcn_s_setprio(1);
#pragma unroll
      for (int rf = 0; rf < 4; ++rf)
#pragma unroll
        for (int cf = 0; cf < 4; ++cf)
          acc[rf][cf] = __builtin_amdgcn_mfma_f32_16x16x32_bf16(af[rf], bfr[cf], acc[rf][cf], 0, 0, 0);
      __builtin_amdgcn_s_setprio(0);
    }
  };

  unsigned short *a0 = As[0], *a1 = As[1], *a2 = As[2];
  unsigned short *b0 = Bs[0], *b1 = Bs[1], *b2 = Bs[2];

  stage(0, a0, b0);
  stage(64, a1, b1);
  VMCNT(6);                                    // tile 0 landed; tile 1 may fly
  __builtin_amdgcn_s_barrier();
  CFENCE();

  for (int kt = 0; kt < DD / 64 - 2; ++kt) {
    stage((kt + 2) * 64, a2, b2);              // prefetch depth 2
    compute_tile(a0, b0);
    VMCNT(6);                                  // all but newest K-tile landed
    __builtin_amdgcn_s_barrier();
    CFENCE();
    unsigned short* t;
    t = a0; a0 = a1; a1 = a2; a2 = t;
    t = b0; b0 = b1; b1 = b2; b2 = t;
  }
  compute_tile(a0, b0);                        // tile NT-2
  VMCNT(0);
  __builtin_amdgcn_s_barrier();
  CFENCE();
  compute_tile(a1, b1);                        // tile NT-1

  // Epilogue: a = gelu_exact(h) * (g+1) * gate, bf16.
#pragma unroll
  for (int rf = 0; rf < 4; ++rf) {
#pragma unroll
    for (int i = 0; i < 4; ++i) {
      int r = wr * 64 + rf * 16 + l4 * 4 + i;
      if (r < nrows) {
        int q = q0 + r;
        float gt = gates[plist[q]];
        unsigned short* orow = abuf + (size_t)q * HH + c0 + wc * 32 + l15;
#pragma unroll
        for (int cf = 0; cf < 2; ++cf) {
          float hv = acc[rf][cf][i];
          float gv = acc[rf][cf + 2][i];
          float av = 0.5f * hv * (1.0f + erff(hv * 0.70710678118654752f)) * (gv + 1.0f) * gt;
          orow[cf * 16] = f2bf(av);
        }
      }
    }
  }
}

// ---------------- GEMM2: down = a @ W2[e], f32 out (sorted order, gate pre-applied) --------
// Same 256x128 depth-2 swizzled structure as GEMM1.
// grid: (40 row-tiles, 8 col-tiles of 128); block 512
__global__ __launch_bounds__(512) void k_gemm2(
    const unsigned short* __restrict__ abuf,   // [P][2048] bf16
    const unsigned short* __restrict__ w2t,    // [E][1024][2048] bf16 ([col][k])
    const int* __restrict__ meta,
    float* __restrict__ down)                  // [P][1024] f32
{
  const int nt = meta[0];
  const int tb = blockIdx.x;
  if (tb >= nt) return;
  const int e  = meta[16 + 2*tb];
  const int q0 = meta[17 + 2*tb];
  const int nrows = min(256, meta[2 + e] - q0);
  const int c0 = blockIdx.y * 128;

  __shared__ unsigned short As[3][256 * 64];   // 96 KB
  __shared__ unsigned short Bs[3][128 * 64];   // 48 KB

  const int tid = threadIdx.x;
  const int wave = tid >> 6, lane = tid & 63;
  const int l15 = lane & 15, l4 = lane >> 4;
  const int wr = wave >> 1, wc = wave & 1;

  const unsigned short* w2e = w2t + (size_t)e * DD * HH;

  const unsigned short* aga[4];
  const unsigned short* bga[2];
#pragma unroll
  for (int i = 0; i < 4; ++i) {
    int c = tid + i * 512;
    int row = c >> 3;                          // 0..255
    int ko = ((c & 7) ^ (row & 7)) * 8;
    int r = row < nrows ? row : 0;
    aga[i] = abuf + (size_t)(q0 + r) * HH + ko;
  }
#pragma unroll
  for (int i = 0; i < 2; ++i) {
    int c = tid + i * 512;
    int row = c >> 3;                          // 0..127
    int ko = ((c & 7) ^ (row & 7)) * 8;
    bga[i] = w2e + (size_t)(c0 + row) * HH + ko;
  }

  f32x4 acc[4][4];
#pragma unroll
  for (int a = 0; a < 4; ++a)
#pragma unroll
    for (int b = 0; b < 4; ++b) acc[a][b] = (f32x4)0.0f;

  auto stage = [&](int kk, unsigned short* pa, unsigned short* pb) {
#pragma unroll
    for (int i = 0; i < 4; ++i) gload16(aga[i] + kk, pa + (tid + i * 512) * 8);
#pragma unroll
    for (int i = 0; i < 2; ++i) gload16(bga[i] + kk, pb + (tid + i * 512) * 8);
  };

  auto compute_tile = [&](const unsigned short* sa, const unsigned short* sb) {
    const char* A8 = (const char*)sa;
    const char* B8 = (const char*)sb;
#pragma unroll
    for (int ks = 0; ks < 2; ++ks) {
      s16x8 af[4], bfr[4];
#pragma unroll
      for (int rf = 0; rf < 4; ++rf) {
        int row = wr * 64 + rf * 16 + l15;
        af[rf] = *(const s16x8*)(A8 + ((row * 128 + ks * 64 + l4 * 16) ^ ((row & 7) << 4)));
      }
#pragma unroll
      for (int cf = 0; cf < 4; ++cf) {
        int row = wc * 64 + cf * 16 + l15;
        bfr[cf] = *(const s16x8*)(B8 + ((row * 128 + ks * 64 + l4 * 16) ^ ((row & 7) << 4)));
      }
      __builtin_amdgcn_s_setprio(1);
#pragma unroll
      for (int rf = 0; rf < 4; ++rf)
#pragma unroll
        for (int cf = 0; cf < 4; ++cf)
          acc[rf][cf] = __builtin_amdgcn_mfma_f32_16x16x32_bf16(af[rf], bfr[cf], acc[rf][cf], 0, 0, 0);
      __builtin_amdgcn_s_setprio(0);
    }
  };

  unsigned short *a0 = As[0], *a1 = As[1], *a2 = As[2];
  unsigned short *b0 = Bs[0], *b1 = Bs[1], *b2 = Bs[2];

  stage(0, a0, b0);
  stage(64, a1, b1);
  VMCNT(6);
  __builtin_amdgcn_s_barrier();
  CFENCE();

  for (int kt = 0; kt < HH / 64 - 2; ++kt) {
    stage((kt + 2) * 64, a2, b2);
    compute_tile(a0, b0);
    VMCNT(6);
    __builtin_amdgcn_s_barrier();
    CFENCE();
    unsigned short* t;
    t = a0; a0 = a1; a1 = a2; a2 = t;
    t = b0; b0 = b1; b1 = b2; b2 = t;
  }
  compute_tile(a0, b0);
  VMCNT(0);
  __builtin_amdgcn_s_barrier();
  CFENCE();
  compute_tile(a1, b1);

#pragma unroll
  for (int rf = 0; rf < 4; ++rf) {
#pragma unroll
    for (int i = 0; i < 4; ++i) {
      int r = wr * 64 + rf * 16 + l4 * 4 + i;
      if (r < nrows) {
        int q = q0 + r;
        float* orow = down + (size_t)q * DD + c0 + wc * 64 + l15;
#pragma unroll
        for (int cf = 0; cf < 4; ++cf) orow[cf * 16] = acc[rf][cf][i];
      }
    }
  }
}

// ---------------- combine: y[t] = down[pos[2t]] + down[pos[2t+1]] ----------------
__global__ void k_combine(const float* __restrict__ down, const int* __restrict__ pos,
                          float* __restrict__ y) {
  int i = blockIdx.x * blockDim.x + threadIdx.x;  // over TT*DD/4
  if (i >= TT * DD / 4) return;
  int t = i >> 8;           // DD/4 = 256 float4 per row
  int c4 = i & 255;
  int qa = pos[2 * t], qb = pos[2 * t + 1];
  float4 a = reinterpret_cast<const float4*>(down + (size_t)qa * DD)[c4];
  float4 b = reinterpret_cast<const float4*>(down + (size_t)qb * DD)[c4];
  float4 o; o.x = a.x + b.x; o.y = a.y + b.y; o.z = a.z + b.z; o.w = a.w + b.w;
  reinterpret_cast<float4*>(y)[i] = o;
}

extern "C" void kernel_launch(void* const* d_in, const int* in_sizes, int n_in,
                              void* d_out, int out_size, void* d_ws, size_t ws_size,
                              hipStream_t stream) {
  const float* x  = (const float*)d_in[0];
  const float* ep = (const float*)d_in[1];
  const int*   ei = (const int*)d_in[2];
  const float* W1 = (const float*)d_in[3];
  const float* W2 = (const float*)d_in[4];
  float* y = (float*)d_out;
  char* ws = (char*)d_ws;

  unsigned short* w1t = (unsigned short*)(ws + W1T_OFF);
  unsigned short* w2t = (unsigned short*)(ws + W2T_OFF);
  unsigned short* xb  = (unsigned short*)(ws + XB_OFF);
  unsigned short* ab  = (unsigned short*)(ws + ABUF_OFF);
  float* down = (float*)(ws + DOWN_OFF);
  int* meta   = (int*)(ws + META_OFF);
  int* plist  = (int*)(ws + PAIR_OFF);
  int* pos    = (int*)(ws + POS_OFF);

  hipLaunchKernelGGL(k_cvt_x, dim3(TT * DD / 4 / 256), dim3(256), 0, stream,
                     x, xb, TT * DD / 4);
  hipLaunchKernelGGL(k_transpose, dim3(CC1 / 64, DD / 64, EE), dim3(256), 0, stream,
                     W1, w1t, DD, CC1);
  hipLaunchKernelGGL(k_transpose, dim3(DD / 64, HH / 64, EE), dim3(256), 0, stream,
                     W2, w2t, HH, DD);
  hipLaunchKernelGGL(k_route, dim3(1), dim3(256), 0, stream, ei, meta, plist, pos);
  hipLaunchKernelGGL(k_gemm1, dim3(40, 32), dim3(512), 0, stream,
                     xb, w1t, ep, meta, plist, ab);
  hipLaunchKernelGGL(k_gemm2, dim3(40, 8), dim3(512), 0, stream,
                     ab, w2t, meta, down);
  hipLaunchKernelGGL(k_combine, dim3(TT * DD / 4 / 256), dim3(256), 0, stream,
                     down, pos, y);
}

// Round 6
// 283.777 us; speedup vs baseline: 1.1078x; 1.0065x over previous
//
#include <hip/hip_runtime.h>
#include <hip/hip_bf16.h>
#include <math.h>

// Problem constants (fixed by the reference)
#define TT 4096   // tokens = B*S
#define PP 8192   // pairs  = TT*K
#define DD 1024   // model dim
#define HH 2048   // expert hidden
#define EE 8      // experts
#define CC1 4096  // 2H (up-proj width)

typedef __attribute__((ext_vector_type(8))) short s16x8;
typedef __attribute__((ext_vector_type(4))) float f32x4;

// ---------------- workspace layout (bytes) ----------------
#define W1T_OFF   0ull                                   // bf16 [E][4096][1024]  64 MB
#define W2T_OFF   (W1T_OFF + (size_t)EE*DD*CC1*2)        // bf16 [E][1024][2048]  32 MB
#define XB_OFF    (W2T_OFF + (size_t)EE*HH*DD*2)         // bf16 [T][1024]         8 MB
#define ABUF_OFF  (XB_OFF  + (size_t)TT*DD*2)            // bf16 [P][2048]        32 MB
#define DOWN_OFF  (ABUF_OFF + (size_t)PP*HH*2)           // f32  [P][1024]        32 MB
#define META_OFF  (DOWN_OFF + (size_t)PP*DD*4)           // int meta[512] (2 KB)
#define PAIR_OFF  (META_OFF + 2048)                      // int [P]
#define POS_OFF   (PAIR_OFF + (size_t)PP*4)              // int [P]

#define VMCNT(N) asm volatile("s_waitcnt vmcnt(" #N ")" ::: "memory")
#define CFENCE() asm volatile("" ::: "memory")

__device__ __forceinline__ unsigned short f2bf(float f) {
  union { float f; unsigned u; } a; a.f = f;
  unsigned u = a.u;
  unsigned r = u + 0x7FFFu + ((u >> 16) & 1u);   // round-to-nearest-even
  return (unsigned short)(r >> 16);
}

// async global->LDS, 16B per lane; LDS dest must be wave-uniform base + lane*16
__device__ __forceinline__ void gload16(const void* g, void* l) {
  __builtin_amdgcn_global_load_lds(
      (const __attribute__((address_space(1))) void*)(uintptr_t)g,
      (__attribute__((address_space(3))) void*)(unsigned)(uintptr_t)l,
      16, 0, 0);
}

// ---------------- x -> bf16 ----------------
__global__ void k_cvt_x(const float* __restrict__ in, unsigned short* __restrict__ out, int n4) {
  int i = blockIdx.x * blockDim.x + threadIdx.x;
  if (i >= n4) return;
  float4 v = reinterpret_cast<const float4*>(in)[i];
  ushort4 o;
  o.x = f2bf(v.x); o.y = f2bf(v.y); o.z = f2bf(v.z); o.w = f2bf(v.w);
  reinterpret_cast<ushort4*>(out)[i] = o;
}

// ---------------- W [R][C] f32 -> Wt [C][R] bf16 (per matrix in grid.z) ----------------
__global__ __launch_bounds__(256) void k_transpose(const float* __restrict__ in,
                                                   unsigned short* __restrict__ out,
                                                   int R, int C) {
  __shared__ float t[64][65];
  const size_t mbase = (size_t)blockIdx.z * (size_t)R * (size_t)C;
  int c0 = blockIdx.x * 64, r0 = blockIdx.y * 64;
  int tid = threadIdx.x;
#pragma unroll
  for (int i = 0; i < 4; ++i) {
    int ch = tid + i * 256;            // 1024 chunks of float4
    int row = ch >> 4, c4 = (ch & 15) * 4;
    float4 v = *reinterpret_cast<const float4*>(&in[mbase + (size_t)(r0 + row) * C + c0 + c4]);
    t[row][c4] = v.x; t[row][c4 + 1] = v.y; t[row][c4 + 2] = v.z; t[row][c4 + 3] = v.w;
  }
  __syncthreads();
#pragma unroll
  for (int i = 0; i < 4; ++i) {
    int ch = tid + i * 256;
    int c = ch >> 4, rb = (ch & 15) * 4;
    ushort4 o;
    o.x = f2bf(t[rb][c]); o.y = f2bf(t[rb + 1][c]);
    o.z = f2bf(t[rb + 2][c]); o.w = f2bf(t[rb + 3][c]);
    *reinterpret_cast<ushort4*>(&out[mbase + (size_t)(c0 + c) * R + r0 + rb]) = o;
  }
}

// ---------------- routing: bucket pairs by expert, 256-row tile list, inverse perm ----------
// meta[0]=ntiles256; meta[1..9]=offsets[0..8]; meta[16+2i]/(17+2i) = (expert,q0)
__global__ void k_route(const int* __restrict__ eidx, int* __restrict__ meta,
                        int* __restrict__ plist, int* __restrict__ pos) {
  __shared__ int cnt[EE], off[EE + 1], cur[EE];
  int tid = threadIdx.x;
  if (tid < EE) { cnt[tid] = 0; cur[tid] = 0; }
  __syncthreads();
  for (int p = tid; p < PP; p += blockDim.x) atomicAdd(&cnt[eidx[p]], 1);
  __syncthreads();
  if (tid == 0) {
    int s = 0;
    for (int e = 0; e < EE; ++e) { off[e] = s; s += cnt[e]; }
    off[EE] = s;
    int n256 = 0;
    for (int e = 0; e < EE; ++e)
      for (int r = 0; r < cnt[e]; r += 256) {
        meta[16 + 2*n256] = e; meta[17 + 2*n256] = off[e] + r; ++n256;
      }
    meta[0] = n256;
    for (int e = 0; e <= EE; ++e) meta[1 + e] = off[e];
  }
  __syncthreads();
  for (int p = tid; p < PP; p += blockDim.x) {
    int e = eidx[p];
    int q = off[e] + atomicAdd(&cur[e], 1);
    plist[q] = p;
    pos[p] = q;
  }
}

// ---------------- GEMM1: up = x @ W1[e], fused GLU + gate, bf16 out (sorted order) ----------
// Phase-granular pipeline (T3+T4): 256x256 tile (128 h-cols + 128 g-cols interleaved in
// 16-col blocks), 8 waves (2M x 4N, 128x64 per wave). Staging unit = half-K (32) of A+B
// (4 gload_lds/thread), 4 circular LDS slots (128 KB), depth-3 issue, counted vmcnt(8),
// one s_barrier per phase, 32 MFMA per phase, T2 both-sides XOR swizzle, T5 setprio.
// grid: (40 row-tiles, 16 col-tiles of 128 h-cols); block 512
__global__ __launch_bounds__(512, 2) void k_gemm1(
    const unsigned short* __restrict__ xb,     // [T][1024] bf16
    const unsigned short* __restrict__ w1t,    // [E][4096][1024] bf16 ([col][k])
    const float* __restrict__ gates,           // [P] f32
    const int* __restrict__ meta,
    const int* __restrict__ plist,
    unsigned short* __restrict__ abuf)         // [P][2048] bf16
{
  const int nt = meta[0];
  const int tb = blockIdx.x;
  if (tb >= nt) return;
  const int e  = meta[16 + 2*tb];
  const int q0 = meta[17 + 2*tb];
  const int nrows = min(256, meta[2 + e] - q0);
  const int c0 = blockIdx.y * 128;             // h-col base

  __shared__ unsigned short As[4][256 * 32];   // 64 KB, slot u&3
  __shared__ unsigned short Bs[4][256 * 32];   // 64 KB

  const int tid = threadIdx.x;                 // 0..511
  const int wave = tid >> 6, lane = tid & 63;
  const int l15 = lane & 15, l4 = lane >> 4;
  const int wm = wave >> 2, wn = wave & 3;     // 2M x 4N wave grid

  const unsigned short* w1e = w1t + (size_t)e * CC1 * DD;

  // staging sources: 2 A-chunks + 2 B-chunks of 16B per thread per half-K unit.
  // chunk c: row = c>>2 (0..255), kc = c&3; global k-slot pre-swizzled kc^(row&3).
  const unsigned short* aga[2];
  const unsigned short* bga[2];
#pragma unroll
  for (int i = 0; i < 2; ++i) {
    int c = tid + i * 512;                     // 0..1023
    int row = c >> 2;
    int kc = c & 3;
    int ko = (kc ^ (row & 3)) * 8;
    int r = row < nrows ? row : 0;
    int p = plist[q0 + r];
    aga[i] = xb + (size_t)(p >> 1) * DD + ko;
    // B LDS row -> global col: 16-row block b; even b = h cols, odd b = matching g cols
    int b = row >> 4, u = row & 15;
    int col = ((b & 1) ? HH : 0) + c0 + (b >> 1) * 16 + u;
    bga[i] = w1e + (size_t)col * DD + ko;
  }

  f32x4 acc[8][4];
#pragma unroll
  for (int a = 0; a < 8; ++a)
#pragma unroll
    for (int b = 0; b < 4; ++b) acc[a][b] = (f32x4)0.0f;

  const int swz = (l4 ^ (l15 & 3)) << 4;       // byte swizzle, thread-invariant

  auto stage = [&](int u) {
    unsigned short* pa = As[u & 3];
    unsigned short* pb = Bs[u & 3];
    const int kk = u * 32;
#pragma unroll
    for (int i = 0; i < 2; ++i) gload16(aga[i] + kk, pa + (tid + i * 512) * 8);
#pragma unroll
    for (int i = 0; i < 2; ++i) gload16(bga[i] + kk, pb + (tid + i * 512) * 8);
  };

  auto phase = [&](int u, bool dostage) {
    const char* A8 = (const char*)As[u & 3];
    const char* B8 = (const char*)Bs[u & 3];
    s16x8 af[8], bfr[4];
#pragma unroll
    for (int rf = 0; rf < 8; ++rf) {
      int row = wm * 128 + rf * 16 + l15;
      af[rf] = *(const s16x8*)(A8 + row * 64 + swz);
    }
#pragma unroll
    for (int cf = 0; cf < 4; ++cf) {
      int brow = wn * 64 + cf * 16 + l15;
      bfr[cf] = *(const s16x8*)(B8 + brow * 64 + swz);
    }
    if (dostage) stage(u + 3);
    __builtin_amdgcn_s_setprio(1);
#pragma unroll
    for (int rf = 0; rf < 8; ++rf)
#pragma unroll
      for (int cf = 0; cf < 4; ++cf)
        acc[rf][cf] = __builtin_amdgcn_mfma_f32_16x16x32_bf16(af[rf], bfr[cf], acc[rf][cf], 0, 0, 0);
    __builtin_amdgcn_s_setprio(0);
  };

  const int NU = DD / 32;                      // 32 half-K units

  stage(0); stage(1); stage(2);                // 12 loads in flight
  for (int u = 0; u < NU - 3; ++u) {
    VMCNT(8);                                  // oldest unit (u) landed; u+1..u+2 may fly
    __builtin_amdgcn_s_barrier();
    CFENCE();
    phase(u, true);                            // + issues stage(u+3) mid-phase
  }
  VMCNT(8); __builtin_amdgcn_s_barrier(); CFENCE();
  phase(NU - 3, false);
  VMCNT(4); __builtin_amdgcn_s_barrier(); CFENCE();
  phase(NU - 2, false);
  VMCNT(0); __builtin_amdgcn_s_barrier(); CFENCE();
  phase(NU - 1, false);

  // Epilogue: a = gelu_exact(h) * (g+1) * gate, bf16.
  // acc[rf][cf]: even cf = h block, odd cf = matching g block (same lanes).
#pragma unroll
  for (int rf = 0; rf < 8; ++rf) {
#pragma unroll
    for (int i = 0; i < 4; ++i) {
      int r = wm * 128 + rf * 16 + l4 * 4 + i;
      if (r < nrows) {
        int q = q0 + r;
        float gt = gates[plist[q]];
        unsigned short* orow = abuf + (size_t)q * HH + c0 + wn * 32 + l15;
#pragma unroll
        for (int j = 0; j < 2; ++j) {
          float hv = acc[rf][2 * j][i];
          float gv = acc[rf][2 * j + 1][i];
          float av = 0.5f * hv * (1.0f + erff(hv * 0.70710678118654752f)) * (gv + 1.0f) * gt;
          orow[j * 16] = f2bf(av);
        }
      }
    }
  }
}

// ---------------- GEMM2: down = a @ W2[e], f32 out (sorted order, gate pre-applied) --------
// 256x128 tile, depth-2 counted-vmcnt structure (no setprio — hurt at this phase depth).
// grid: (40 row-tiles, 8 col-tiles of 128); block 512
__global__ __launch_bounds__(512) void k_gemm2(
    const unsigned short* __restrict__ abuf,   // [P][2048] bf16
    const unsigned short* __restrict__ w2t,    // [E][1024][2048] bf16 ([col][k])
    const int* __restrict__ meta,
    float* __restrict__ down)                  // [P][1024] f32
{
  const int nt = meta[0];
  const int tb = blockIdx.x;
  if (tb >= nt) return;
  const int e  = meta[16 + 2*tb];
  const int q0 = meta[17 + 2*tb];
  const int nrows = min(256, meta[2 + e] - q0);
  const int c0 = blockIdx.y * 128;

  __shared__ unsigned short As[3][256 * 64];   // 96 KB
  __shared__ unsigned short Bs[3][128 * 64];   // 48 KB

  const int tid = threadIdx.x;
  const int wave = tid >> 6, lane = tid & 63;
  const int l15 = lane & 15, l4 = lane >> 4;
  const int wr = wave >> 1, wc = wave & 1;

  const unsigned short* w2e = w2t + (size_t)e * DD * HH;

  const unsigned short* aga[4];
  const unsigned short* bga[2];
#pragma unroll
  for (int i = 0; i < 4; ++i) {
    int c = tid + i * 512;
    int row = c >> 3;                          // 0..255
    int ko = ((c & 7) ^ (row & 7)) * 8;
    int r = row < nrows ? row : 0;
    aga[i] = abuf + (size_t)(q0 + r) * HH + ko;
  }
#pragma unroll
  for (int i = 0; i < 2; ++i) {
    int c = tid + i * 512;
    int row = c >> 3;                          // 0..127
    int ko = ((c & 7) ^ (row & 7)) * 8;
    bga[i] = w2e + (size_t)(c0 + row) * HH + ko;
  }

  f32x4 acc[4][4];
#pragma unroll
  for (int a = 0; a < 4; ++a)
#pragma unroll
    for (int b = 0; b < 4; ++b) acc[a][b] = (f32x4)0.0f;

  auto stage = [&](int kk, unsigned short* pa, unsigned short* pb) {
#pragma unroll
    for (int i = 0; i < 4; ++i) gload16(aga[i] + kk, pa + (tid + i * 512) * 8);
#pragma unroll
    for (int i = 0; i < 2; ++i) gload16(bga[i] + kk, pb + (tid + i * 512) * 8);
  };

  auto compute_tile = [&](const unsigned short* sa, const unsigned short* sb) {
    const char* A8 = (const char*)sa;
    const char* B8 = (const char*)sb;
#pragma unroll
    for (int ks = 0; ks < 2; ++ks) {
      s16x8 af[4], bfr[4];
#pragma unroll
      for (int rf = 0; rf < 4; ++rf) {
        int row = wr * 64 + rf * 16 + l15;
        af[rf] = *(const s16x8*)(A8 + ((row * 128 + ks * 64 + l4 * 16) ^ ((row & 7) << 4)));
      }
#pragma unroll
      for (int cf = 0; cf < 4; ++cf) {
        int row = wc * 64 + cf * 16 + l15;
        bfr[cf] = *(const s16x8*)(B8 + ((row * 128 + ks * 64 + l4 * 16) ^ ((row & 7) << 4)));
      }
#pragma unroll
      for (int rf = 0; rf < 4; ++rf)
#pragma unroll
        for (int cf = 0; cf < 4; ++cf)
          acc[rf][cf] = __builtin_amdgcn_mfma_f32_16x16x32_bf16(af[rf], bfr[cf], acc[rf][cf], 0, 0, 0);
    }
  };

  unsigned short *a0 = As[0], *a1 = As[1], *a2 = As[2];
  unsigned short *b0 = Bs[0], *b1 = Bs[1], *b2 = Bs[2];

  stage(0, a0, b0);
  stage(64, a1, b1);
  VMCNT(6);
  __builtin_amdgcn_s_barrier();
  CFENCE();

  for (int kt = 0; kt < HH / 64 - 2; ++kt) {
    stage((kt + 2) * 64, a2, b2);
    compute_tile(a0, b0);
    VMCNT(6);
    __builtin_amdgcn_s_barrier();
    CFENCE();
    unsigned short* t;
    t = a0; a0 = a1; a1 = a2; a2 = t;
    t = b0; b0 = b1; b1 = b2; b2 = t;
  }
  compute_tile(a0, b0);
  VMCNT(0);
  __builtin_amdgcn_s_barrier();
  CFENCE();
  compute_tile(a1, b1);

#pragma unroll
  for (int rf = 0; rf < 4; ++rf) {
#pragma unroll
    for (int i = 0; i < 4; ++i) {
      int r = wr * 64 + rf * 16 + l4 * 4 + i;
      if (r < nrows) {
        int q = q0 + r;
        float* orow = down + (size_t)q * DD + c0 + wc * 64 + l15;
#pragma unroll
        for (int cf = 0; cf < 4; ++cf) orow[cf * 16] = acc[rf][cf][i];
      }
    }
  }
}

// ---------------- combine: y[t] = down[pos[2t]] + down[pos[2t+1]] ----------------
__global__ void k_combine(const float* __restrict__ down, const int* __restrict__ pos,
                          float* __restrict__ y) {
  int i = blockIdx.x * blockDim.x + threadIdx.x;  // over TT*DD/4
  if (i >= TT * DD / 4) return;
  int t = i >> 8;           // DD/4 = 256 float4 per row
  int c4 = i & 255;
  int qa = pos[2 * t], qb = pos[2 * t + 1];
  float4 a = reinterpret_cast<const float4*>(down + (size_t)qa * DD)[c4];
  float4 b = reinterpret_cast<const float4*>(down + (size_t)qb * DD)[c4];
  float4 o; o.x = a.x + b.x; o.y = a.y + b.y; o.z = a.z + b.z; o.w = a.w + b.w;
  reinterpret_cast<float4*>(y)[i] = o;
}

extern "C" void kernel_launch(void* const* d_in, const int* in_sizes, int n_in,
                              void* d_out, int out_size, void* d_ws, size_t ws_size,
                              hipStream_t stream) {
  const float* x  = (const float*)d_in[0];
  const float* ep = (const float*)d_in[1];
  const int*   ei = (const int*)d_in[2];
  const float* W1 = (const float*)d_in[3];
  const float* W2 = (const float*)d_in[4];
  float* y = (float*)d_out;
  char* ws = (char*)d_ws;

  unsigned short* w1t = (unsigned short*)(ws + W1T_OFF);
  unsigned short* w2t = (unsigned short*)(ws + W2T_OFF);
  unsigned short* xb  = (unsigned short*)(ws + XB_OFF);
  unsigned short* ab  = (unsigned short*)(ws + ABUF_OFF);
  float* down = (float*)(ws + DOWN_OFF);
  int* meta   = (int*)(ws + META_OFF);
  int* plist  = (int*)(ws + PAIR_OFF);
  int* pos    = (int*)(ws + POS_OFF);

  hipLaunchKernelGGL(k_cvt_x, dim3(TT * DD / 4 / 256), dim3(256), 0, stream,
                     x, xb, TT * DD / 4);
  hipLaunchKernelGGL(k_transpose, dim3(CC1 / 64, DD / 64, EE), dim3(256), 0, stream,
                     W1, w1t, DD, CC1);
  hipLaunchKernelGGL(k_transpose, dim3(DD / 64, HH / 64, EE), dim3(256), 0, stream,
                     W2, w2t, HH, DD);
  hipLaunchKernelGGL(k_route, dim3(1), dim3(256), 0, stream, ei, meta, plist, pos);
  hipLaunchKernelGGL(k_gemm1, dim3(40, 16), dim3(512), 0, stream,
                     xb, w1t, ep, meta, plist, ab);
  hipLaunchKernelGGL(k_gemm2, dim3(40, 8), dim3(512), 0, stream,
                     ab, w2t, meta, down);
  hipLaunchKernelGGL(k_combine, dim3(TT * DD / 4 / 256), dim3(256), 0, stream,
                     down, pos, y);
}

// Round 7
// 270.091 us; speedup vs baseline: 1.1639x; 1.0507x over previous
//
#include <hip/hip_runtime.h>
#include <hip/hip_bf16.h>
#include <math.h>

// Problem constants (fixed by the reference)
#define TT 4096   // tokens = B*S
#define PP 8192   // pairs  = TT*K
#define DD 1024   // model dim
#define HH 2048   // expert hidden
#define EE 8      // experts
#define CC1 4096  // 2H (up-proj width)

typedef __attribute__((ext_vector_type(8))) short s16x8;
typedef __attribute__((ext_vector_type(4))) float f32x4;

// ---------------- workspace layout (bytes) ----------------
#define W1T_OFF   0ull                                   // bf16 [E][4096][1024]  64 MB
#define W2T_OFF   (W1T_OFF + (size_t)EE*DD*CC1*2)        // bf16 [E][1024][2048]  32 MB
#define XB_OFF    (W2T_OFF + (size_t)EE*HH*DD*2)         // bf16 [T][1024]         8 MB
#define ABUF_OFF  (XB_OFF  + (size_t)TT*DD*2)            // bf16 [P][2048]        32 MB
#define DOWN_OFF  (ABUF_OFF + (size_t)PP*HH*2)           // bf16 [2][P][1024]     32 MB
#define META_OFF  (DOWN_OFF + (size_t)2*PP*DD*2)         // int meta[512] (2 KB)
#define PAIR_OFF  (META_OFF + 2048)                      // int [P]
#define POS_OFF   (PAIR_OFF + (size_t)PP*4)              // int [P]

#define VMCNT(N) asm volatile("s_waitcnt vmcnt(" #N ")" ::: "memory")
#define CFENCE() asm volatile("" ::: "memory")

__device__ __forceinline__ unsigned short f2bf(float f) {
  union { float f; unsigned u; } a; a.f = f;
  unsigned u = a.u;
  unsigned r = u + 0x7FFFu + ((u >> 16) & 1u);   // round-to-nearest-even
  return (unsigned short)(r >> 16);
}

__device__ __forceinline__ float bf2f(unsigned short s) {
  union { unsigned u; float f; } a; a.u = ((unsigned)s) << 16;
  return a.f;
}

// async global->LDS, 16B per lane; LDS dest must be wave-uniform base + lane*16
__device__ __forceinline__ void gload16(const void* g, void* l) {
  __builtin_amdgcn_global_load_lds(
      (const __attribute__((address_space(1))) void*)(uintptr_t)g,
      (__attribute__((address_space(3))) void*)(unsigned)(uintptr_t)l,
      16, 0, 0);
}

// ---------------- x -> bf16 ----------------
__global__ void k_cvt_x(const float* __restrict__ in, unsigned short* __restrict__ out, int n4) {
  int i = blockIdx.x * blockDim.x + threadIdx.x;
  if (i >= n4) return;
  float4 v = reinterpret_cast<const float4*>(in)[i];
  ushort4 o;
  o.x = f2bf(v.x); o.y = f2bf(v.y); o.z = f2bf(v.z); o.w = f2bf(v.w);
  reinterpret_cast<ushort4*>(out)[i] = o;
}

// ---------------- W [R][C] f32 -> Wt [C][R] bf16 (per matrix in grid.z) ----------------
__global__ __launch_bounds__(256) void k_transpose(const float* __restrict__ in,
                                                   unsigned short* __restrict__ out,
                                                   int R, int C) {
  __shared__ float t[64][65];
  const size_t mbase = (size_t)blockIdx.z * (size_t)R * (size_t)C;
  int c0 = blockIdx.x * 64, r0 = blockIdx.y * 64;
  int tid = threadIdx.x;
#pragma unroll
  for (int i = 0; i < 4; ++i) {
    int ch = tid + i * 256;            // 1024 chunks of float4
    int row = ch >> 4, c4 = (ch & 15) * 4;
    float4 v = *reinterpret_cast<const float4*>(&in[mbase + (size_t)(r0 + row) * C + c0 + c4]);
    t[row][c4] = v.x; t[row][c4 + 1] = v.y; t[row][c4 + 2] = v.z; t[row][c4 + 3] = v.w;
  }
  __syncthreads();
#pragma unroll
  for (int i = 0; i < 4; ++i) {
    int ch = tid + i * 256;
    int c = ch >> 4, rb = (ch & 15) * 4;
    ushort4 o;
    o.x = f2bf(t[rb][c]); o.y = f2bf(t[rb + 1][c]);
    o.z = f2bf(t[rb + 2][c]); o.w = f2bf(t[rb + 3][c]);
    *reinterpret_cast<ushort4*>(&out[mbase + (size_t)(c0 + c) * R + r0 + rb]) = o;
  }
}

// ---------------- routing: bucket pairs by expert, 256-row tile list, inverse perm ----------
// meta[0]=ntiles256; meta[1..9]=offsets[0..8]; meta[16+2i]/(17+2i) = (expert,q0)
__global__ void k_route(const int* __restrict__ eidx, int* __restrict__ meta,
                        int* __restrict__ plist, int* __restrict__ pos) {
  __shared__ int cnt[EE], off[EE + 1], cur[EE];
  int tid = threadIdx.x;
  if (tid < EE) { cnt[tid] = 0; cur[tid] = 0; }
  __syncthreads();
  for (int p = tid; p < PP; p += blockDim.x) atomicAdd(&cnt[eidx[p]], 1);
  __syncthreads();
  if (tid == 0) {
    int s = 0;
    for (int e = 0; e < EE; ++e) { off[e] = s; s += cnt[e]; }
    off[EE] = s;
    int n256 = 0;
    for (int e = 0; e < EE; ++e)
      for (int r = 0; r < cnt[e]; r += 256) {
        meta[16 + 2*n256] = e; meta[17 + 2*n256] = off[e] + r; ++n256;
      }
    meta[0] = n256;
    for (int e = 0; e <= EE; ++e) meta[1 + e] = off[e];
  }
  __syncthreads();
  for (int p = tid; p < PP; p += blockDim.x) {
    int e = eidx[p];
    int q = off[e] + atomicAdd(&cur[e], 1);
    plist[q] = p;
    pos[p] = q;
  }
}

// ---------------- GEMM1: up = x @ W1[e], fused GLU + gate, bf16 out (sorted order) ----------
// 256x128 tile (64 h-cols + paired 64 g-cols), BK=64, 8 waves (4Mx2N),
// depth-2 prefetch (3 LDS buffers), counted vmcnt(6) + raw s_barrier,
// T2 XOR-swizzle (linear gload_lds dest + pre-swizzled global src + swizzled ds_read).
// grid: (40 row-tiles, 32 col-tiles); block 512   [round-4 proven structure]
__global__ __launch_bounds__(512) void k_gemm1(
    const unsigned short* __restrict__ xb,     // [T][1024] bf16
    const unsigned short* __restrict__ w1t,    // [E][4096][1024] bf16 ([col][k])
    const float* __restrict__ gates,           // [P] f32
    const int* __restrict__ meta,
    const int* __restrict__ plist,
    unsigned short* __restrict__ abuf)         // [P][2048] bf16
{
  const int nt = meta[0];
  const int tb = blockIdx.x;
  if (tb >= nt) return;
  const int e  = meta[16 + 2*tb];
  const int q0 = meta[17 + 2*tb];
  const int nrows = min(256, meta[2 + e] - q0);
  const int c0 = blockIdx.y * 64;              // h-col base

  __shared__ unsigned short As[3][256 * 64];   // 96 KB
  __shared__ unsigned short Bs[3][128 * 64];   // 48 KB

  const int tid = threadIdx.x;                 // 0..511
  const int wave = tid >> 6, lane = tid & 63;
  const int l15 = lane & 15, l4 = lane >> 4;
  const int wr = wave >> 1, wc = wave & 1;     // 4M x 2N wave grid

  const unsigned short* w1e = w1t + (size_t)e * CC1 * DD;

  const unsigned short* aga[4];
  const unsigned short* bga[2];
#pragma unroll
  for (int i = 0; i < 4; ++i) {
    int c = tid + i * 512;                     // 0..2047
    int row = c >> 3;                          // 0..255
    int ko = ((c & 7) ^ (row & 7)) * 8;
    int r = row < nrows ? row : 0;
    int p = plist[q0 + r];
    aga[i] = xb + (size_t)(p >> 1) * DD + ko;
  }
#pragma unroll
  for (int i = 0; i < 2; ++i) {
    int c = tid + i * 512;                     // 0..1023
    int row = c >> 3;                          // 0..127
    int ko = ((c & 7) ^ (row & 7)) * 8;
    int u = row & 63, wcq = row >> 6;
    int col = (u < 32) ? (c0 + wcq * 32 + u) : (HH + c0 + wcq * 32 + (u - 32));
    bga[i] = w1e + (size_t)col * DD + ko;
  }

  f32x4 acc[4][4];
#pragma unroll
  for (int a = 0; a < 4; ++a)
#pragma unroll
    for (int b = 0; b < 4; ++b) acc[a][b] = (f32x4)0.0f;

  auto stage = [&](int kk, unsigned short* pa, unsigned short* pb) {
#pragma unroll
    for (int i = 0; i < 4; ++i) gload16(aga[i] + kk, pa + (tid + i * 512) * 8);
#pragma unroll
    for (int i = 0; i < 2; ++i) gload16(bga[i] + kk, pb + (tid + i * 512) * 8);
  };

  auto compute_tile = [&](const unsigned short* sa, const unsigned short* sb) {
    const char* A8 = (const char*)sa;
    const char* B8 = (const char*)sb;
#pragma unroll
    for (int ks = 0; ks < 2; ++ks) {
      s16x8 af[4], bfr[4];
#pragma unroll
      for (int rf = 0; rf < 4; ++rf) {
        int row = wr * 64 + rf * 16 + l15;
        af[rf] = *(const s16x8*)(A8 + ((row * 128 + ks * 64 + l4 * 16) ^ ((row & 7) << 4)));
      }
#pragma unroll
      for (int cf = 0; cf < 4; ++cf) {
        int row = wc * 64 + cf * 16 + l15;
        bfr[cf] = *(const s16x8*)(B8 + ((row * 128 + ks * 64 + l4 * 16) ^ ((row & 7) << 4)));
      }
#pragma unroll
      for (int rf = 0; rf < 4; ++rf)
#pragma unroll
        for (int cf = 0; cf < 4; ++cf)
          acc[rf][cf] = __builtin_amdgcn_mfma_f32_16x16x32_bf16(af[rf], bfr[cf], acc[rf][cf], 0, 0, 0);
    }
  };

  unsigned short *a0 = As[0], *a1 = As[1], *a2 = As[2];
  unsigned short *b0 = Bs[0], *b1 = Bs[1], *b2 = Bs[2];

  stage(0, a0, b0);
  stage(64, a1, b1);
  VMCNT(6);                                    // tile 0 landed; tile 1 may fly
  __builtin_amdgcn_s_barrier();
  CFENCE();

  for (int kt = 0; kt < DD / 64 - 2; ++kt) {
    stage((kt + 2) * 64, a2, b2);              // prefetch depth 2
    compute_tile(a0, b0);
    VMCNT(6);                                  // all but newest K-tile landed
    __builtin_amdgcn_s_barrier();
    CFENCE();
    unsigned short* t;
    t = a0; a0 = a1; a1 = a2; a2 = t;
    t = b0; b0 = b1; b1 = b2; b2 = t;
  }
  compute_tile(a0, b0);                        // tile NT-2
  VMCNT(0);
  __builtin_amdgcn_s_barrier();
  CFENCE();
  compute_tile(a1, b1);                        // tile NT-1

  // Epilogue: a = gelu_exact(h) * (g+1) * gate, bf16.
#pragma unroll
  for (int rf = 0; rf < 4; ++rf) {
#pragma unroll
    for (int i = 0; i < 4; ++i) {
      int r = wr * 64 + rf * 16 + l4 * 4 + i;
      if (r < nrows) {
        int q = q0 + r;
        float gt = gates[plist[q]];
        unsigned short* orow = abuf + (size_t)q * HH + c0 + wc * 32 + l15;
#pragma unroll
        for (int cf = 0; cf < 2; ++cf) {
          float hv = acc[rf][cf][i];
          float gv = acc[rf][cf + 2][i];
          float av = 0.5f * hv * (1.0f + erff(hv * 0.70710678118654752f)) * (gv + 1.0f) * gt;
          orow[cf * 16] = f2bf(av);
        }
      }
    }
  }
}

// ---------------- GEMM2: down_z = a @ W2[e][kz:kz+1024], bf16 partials (K-split 2) --------
// Same 256x128 depth-2 counted-vmcnt swizzled structure; blockIdx.z selects K-half.
// grid: (40 row-tiles, 8 col-tiles of 128, 2 K-halves); block 512
__global__ __launch_bounds__(512) void k_gemm2(
    const unsigned short* __restrict__ abuf,   // [P][2048] bf16
    const unsigned short* __restrict__ w2t,    // [E][1024][2048] bf16 ([col][k])
    const int* __restrict__ meta,
    unsigned short* __restrict__ down)         // [2][P][1024] bf16
{
  const int nt = meta[0];
  const int tb = blockIdx.x;
  if (tb >= nt) return;
  const int e  = meta[16 + 2*tb];
  const int q0 = meta[17 + 2*tb];
  const int nrows = min(256, meta[2 + e] - q0);
  const int c0 = blockIdx.y * 128;
  const int kz = blockIdx.z * (HH / 2);        // K-half base

  __shared__ unsigned short As[3][256 * 64];   // 96 KB
  __shared__ unsigned short Bs[3][128 * 64];   // 48 KB

  const int tid = threadIdx.x;
  const int wave = tid >> 6, lane = tid & 63;
  const int l15 = lane & 15, l4 = lane >> 4;
  const int wr = wave >> 1, wc = wave & 1;

  const unsigned short* w2e = w2t + (size_t)e * DD * HH;

  const unsigned short* aga[4];
  const unsigned short* bga[2];
#pragma unroll
  for (int i = 0; i < 4; ++i) {
    int c = tid + i * 512;
    int row = c >> 3;                          // 0..255
    int ko = ((c & 7) ^ (row & 7)) * 8;
    int r = row < nrows ? row : 0;
    aga[i] = abuf + (size_t)(q0 + r) * HH + kz + ko;
  }
#pragma unroll
  for (int i = 0; i < 2; ++i) {
    int c = tid + i * 512;
    int row = c >> 3;                          // 0..127
    int ko = ((c & 7) ^ (row & 7)) * 8;
    bga[i] = w2e + (size_t)(c0 + row) * HH + kz + ko;
  }

  f32x4 acc[4][4];
#pragma unroll
  for (int a = 0; a < 4; ++a)
#pragma unroll
    for (int b = 0; b < 4; ++b) acc[a][b] = (f32x4)0.0f;

  auto stage = [&](int kk, unsigned short* pa, unsigned short* pb) {
#pragma unroll
    for (int i = 0; i < 4; ++i) gload16(aga[i] + kk, pa + (tid + i * 512) * 8);
#pragma unroll
    for (int i = 0; i < 2; ++i) gload16(bga[i] + kk, pb + (tid + i * 512) * 8);
  };

  auto compute_tile = [&](const unsigned short* sa, const unsigned short* sb) {
    const char* A8 = (const char*)sa;
    const char* B8 = (const char*)sb;
#pragma unroll
    for (int ks = 0; ks < 2; ++ks) {
      s16x8 af[4], bfr[4];
#pragma unroll
      for (int rf = 0; rf < 4; ++rf) {
        int row = wr * 64 + rf * 16 + l15;
        af[rf] = *(const s16x8*)(A8 + ((row * 128 + ks * 64 + l4 * 16) ^ ((row & 7) << 4)));
      }
#pragma unroll
      for (int cf = 0; cf < 4; ++cf) {
        int row = wc * 64 + cf * 16 + l15;
        bfr[cf] = *(const s16x8*)(B8 + ((row * 128 + ks * 64 + l4 * 16) ^ ((row & 7) << 4)));
      }
#pragma unroll
      for (int rf = 0; rf < 4; ++rf)
#pragma unroll
        for (int cf = 0; cf < 4; ++cf)
          acc[rf][cf] = __builtin_amdgcn_mfma_f32_16x16x32_bf16(af[rf], bfr[cf], acc[rf][cf], 0, 0, 0);
    }
  };

  unsigned short *a0 = As[0], *a1 = As[1], *a2 = As[2];
  unsigned short *b0 = Bs[0], *b1 = Bs[1], *b2 = Bs[2];

  stage(0, a0, b0);
  stage(64, a1, b1);
  VMCNT(6);
  __builtin_amdgcn_s_barrier();
  CFENCE();

  const int NT = (HH / 2) / 64;                // 16 K-tiles per half
  for (int kt = 0; kt < NT - 2; ++kt) {
    stage((kt + 2) * 64, a2, b2);
    compute_tile(a0, b0);
    VMCNT(6);
    __builtin_amdgcn_s_barrier();
    CFENCE();
    unsigned short* t;
    t = a0; a0 = a1; a1 = a2; a2 = t;
    t = b0; b0 = b1; b1 = b2; b2 = t;
  }
  compute_tile(a0, b0);
  VMCNT(0);
  __builtin_amdgcn_s_barrier();
  CFENCE();
  compute_tile(a1, b1);

  unsigned short* dz = down + (size_t)blockIdx.z * PP * DD;
#pragma unroll
  for (int rf = 0; rf < 4; ++rf) {
#pragma unroll
    for (int i = 0; i < 4; ++i) {
      int r = wr * 64 + rf * 16 + l4 * 4 + i;
      if (r < nrows) {
        int q = q0 + r;
        unsigned short* orow = dz + (size_t)q * DD + c0 + wc * 64 + l15;
#pragma unroll
        for (int cf = 0; cf < 4; ++cf) orow[cf * 16] = f2bf(acc[rf][cf][i]);
      }
    }
  }
}

// ---------------- combine: y[t] = sum over {pair a,b} x {K-half 0,1} of bf16 partials -----
__global__ void k_combine(const unsigned short* __restrict__ down, const int* __restrict__ pos,
                          float* __restrict__ y) {
  int i = blockIdx.x * blockDim.x + threadIdx.x;  // over TT*DD/8
  if (i >= TT * DD / 8) return;
  int t = i >> 7;            // DD/8 = 128 chunks per row
  int c8 = (i & 127) * 8;
  int qa = pos[2 * t], qb = pos[2 * t + 1];
  const unsigned short* d0 = down;
  const unsigned short* d1 = down + (size_t)PP * DD;
  s16x8 va0 = *reinterpret_cast<const s16x8*>(d0 + (size_t)qa * DD + c8);
  s16x8 va1 = *reinterpret_cast<const s16x8*>(d1 + (size_t)qa * DD + c8);
  s16x8 vb0 = *reinterpret_cast<const s16x8*>(d0 + (size_t)qb * DD + c8);
  s16x8 vb1 = *reinterpret_cast<const s16x8*>(d1 + (size_t)qb * DD + c8);
  float o[8];
#pragma unroll
  for (int j = 0; j < 8; ++j)
    o[j] = bf2f((unsigned short)va0[j]) + bf2f((unsigned short)va1[j]) +
           bf2f((unsigned short)vb0[j]) + bf2f((unsigned short)vb1[j]);
  float4* yo = reinterpret_cast<float4*>(y + (size_t)t * DD + c8);
  yo[0] = (float4){o[0], o[1], o[2], o[3]};
  yo[1] = (float4){o[4], o[5], o[6], o[7]};
}

extern "C" void kernel_launch(void* const* d_in, const int* in_sizes, int n_in,
                              void* d_out, int out_size, void* d_ws, size_t ws_size,
                              hipStream_t stream) {
  const float* x  = (const float*)d_in[0];
  const float* ep = (const float*)d_in[1];
  const int*   ei = (const int*)d_in[2];
  const float* W1 = (const float*)d_in[3];
  const float* W2 = (const float*)d_in[4];
  float* y = (float*)d_out;
  char* ws = (char*)d_ws;

  unsigned short* w1t = (unsigned short*)(ws + W1T_OFF);
  unsigned short* w2t = (unsigned short*)(ws + W2T_OFF);
  unsigned short* xb  = (unsigned short*)(ws + XB_OFF);
  unsigned short* ab  = (unsigned short*)(ws + ABUF_OFF);
  unsigned short* down = (unsigned short*)(ws + DOWN_OFF);
  int* meta   = (int*)(ws + META_OFF);
  int* plist  = (int*)(ws + PAIR_OFF);
  int* pos    = (int*)(ws + POS_OFF);

  hipLaunchKernelGGL(k_cvt_x, dim3(TT * DD / 4 / 256), dim3(256), 0, stream,
                     x, xb, TT * DD / 4);
  hipLaunchKernelGGL(k_transpose, dim3(CC1 / 64, DD / 64, EE), dim3(256), 0, stream,
                     W1, w1t, DD, CC1);
  hipLaunchKernelGGL(k_transpose, dim3(DD / 64, HH / 64, EE), dim3(256), 0, stream,
                     W2, w2t, HH, DD);
  hipLaunchKernelGGL(k_route, dim3(1), dim3(256), 0, stream, ei, meta, plist, pos);
  hipLaunchKernelGGL(k_gemm1, dim3(40, 32), dim3(512), 0, stream,
                     xb, w1t, ep, meta, plist, ab);
  hipLaunchKernelGGL(k_gemm2, dim3(40, 8, 2), dim3(512), 0, stream,
                     ab, w2t, meta, down);
  hipLaunchKernelGGL(k_combine, dim3(TT * DD / 8 / 256), dim3(256), 0, stream,
                     down, pos, y);
}